// Round 5
// baseline (274.108 us; speedup 1.0000x reference)
//
#include <hip/hip_runtime.h>
#include <math.h>

// NoisyTopKGating: out[N,64] = scatter(softmax(top2(x@W^T + b + noise)))
// N=131072, D=1024, E=64, K=2, NOISE_STD=1.0
//
// Round 5: barrier-free split-bf16 MFMA. Round 4 was latency-bound (~2.7 TB/s)
// on the per-chunk LDS-staging barriers (32x vmcnt(0) drains). W-hi/lo (256KB,
// L2-resident) is re-laid FRAGMENT-MAJOR in d_ws: per (kstep, colhalf, hi/lo)
// a 1KB block where lane l reads its 16B B-fragment at base+l*16 (coalesced).
// Zero LDS, zero __syncthreads in the GEMM -> compiler pipelines HBM x-loads
// freely. logits = xh*wh + xh*wl + xl*wh (err ~4e-6 << TAU). fp64 repair pass
// for rows with gap(#2,#3) < TAU (proven rounds 3-4).

#define NEXP   64
#define BLOCK  256
#define TILE_M 128
#define DFIX   1024
#define NKSTEP 64        // D / 16
#define TAU    1e-3f
#define CAP    4096
#define WS_W_OFF 32768   // frag-major W image at d_ws + 32 KB (flags below)

typedef __attribute__((ext_vector_type(8)))  short bf16x8;
typedef __attribute__((ext_vector_type(16))) float f32x16;

__device__ __forceinline__ bool beats(float v, int e, float vo, int eo) {
    // jax.lax.top_k ordering: higher value wins, lower index on tie
    return (v > vo) || (v == vo && e < eo);
}

// Split two fp32 into packed bf16-hi pair and bf16-lo (residual) pair, by truncation.
__device__ __forceinline__ void split2(float f0, float f1, unsigned int& hi, unsigned int& lo) {
    unsigned int u0 = __float_as_uint(f0), u1 = __float_as_uint(f1);
    unsigned int h0 = u0 & 0xFFFF0000u,  h1 = u1 & 0xFFFF0000u;
    float l0 = f0 - __uint_as_float(h0);
    float l1 = f1 - __uint_as_float(h1);
    hi = (u0 >> 16) | h1;
    lo = (__float_as_uint(l0) >> 16) | (__float_as_uint(l1) & 0xFFFF0000u);
}

// W (64x1024 fp32) -> frag-major bf16 hi/lo image (256 KB):
// frag id f = kk*4 + g*2 + h  (kk = k-step 0..63, g = expert-half, h: 0=hi 1=lo)
// lane l of frag f holds W[e = g*32 + (l&31)][k = kk*16 + (l>>5)*8 .. +8] (16B).
__global__ void convW_kernel(const float* __restrict__ W, char* __restrict__ wsW) {
    const int e = blockIdx.x;        // 0..63
    const int t = threadIdx.x;       // 0..127 = global k-octet
    const float* wp = W + e * DFIX + t * 8;
    float4 a  = *(const float4*)wp;
    float4 bq = *(const float4*)(wp + 4);
    unsigned int h[4], l[4];
    split2(a.x,  a.y,  h[0], l[0]);
    split2(a.z,  a.w,  h[1], l[1]);
    split2(bq.x, bq.y, h[2], l[2]);
    split2(bq.z, bq.w, h[3], l[3]);
    const int kk   = t >> 1;         // k-step 0..63
    const int lh   = t & 1;          // k-octet within k-step
    const int lane = lh * 32 + (e & 31);
    const int g    = e >> 5;
    char* base = wsW + (size_t)(kk * 4 + g * 2) * 1024 + lane * 16;
    *(uint4*)(base)        = make_uint4(h[0], h[1], h[2], h[3]);  // h=0 (hi)
    *(uint4*)(base + 1024) = make_uint4(l[0], l[1], l[2], l[3]);  // h=1 (lo)
}

__global__ __launch_bounds__(BLOCK, 4)
void gate_mfma(const float* __restrict__ x, const float* __restrict__ bvec,
               const float* __restrict__ noise, const char* __restrict__ wsW,
               float* __restrict__ out, unsigned int* __restrict__ flags) {
    const int tid  = threadIdx.x;
    const int wv   = tid >> 6;       // wave 0..3 -> rows [32wv, 32wv+32)
    const int lane = tid & 63;
    const int e0   = lane & 31;      // expert col within half / A-row within wave
    const int lh   = lane >> 5;      // k-octet half selector
    const int rowBase = blockIdx.x * TILE_M + wv * 32;

    const float* xrow  = x + (size_t)(rowBase + e0) * DFIX + lh * 8;  // A row, this lane
    const char*  wfrag = wsW + lane * 16;                              // B frag base, this lane

    f32x16 acc0 = (f32x16)0.0f;      // experts 0..31
    f32x16 acc1 = (f32x16)0.0f;      // experts 32..63

    #pragma unroll 4
    for (int kk = 0; kk < NKSTEP; kk++) {
        const float4 xa = *(const float4*)(xrow + kk * 16);
        const float4 xb = *(const float4*)(xrow + kk * 16 + 4);

        const char* fb = wfrag + (size_t)(kk * 4) * 1024;
        union { bf16x8 v; int4 q; } b0h, b0l, b1h, b1l;
        b0h.q = *(const int4*)(fb);          // g=0, hi
        b0l.q = *(const int4*)(fb + 1024);   // g=0, lo
        b1h.q = *(const int4*)(fb + 2048);   // g=1, hi
        b1l.q = *(const int4*)(fb + 3072);   // g=1, lo

        union { bf16x8 v; unsigned int u[4]; } ah, al;
        split2(xa.x, xa.y, ah.u[0], al.u[0]);
        split2(xa.z, xa.w, ah.u[1], al.u[1]);
        split2(xb.x, xb.y, ah.u[2], al.u[2]);
        split2(xb.z, xb.w, ah.u[3], al.u[3]);

        acc0 = __builtin_amdgcn_mfma_f32_32x32x16_bf16(ah.v, b0h.v, acc0, 0, 0, 0);
        acc1 = __builtin_amdgcn_mfma_f32_32x32x16_bf16(ah.v, b1h.v, acc1, 0, 0, 0);
        acc0 = __builtin_amdgcn_mfma_f32_32x32x16_bf16(ah.v, b0l.v, acc0, 0, 0, 0);
        acc1 = __builtin_amdgcn_mfma_f32_32x32x16_bf16(ah.v, b1l.v, acc1, 0, 0, 0);
        acc0 = __builtin_amdgcn_mfma_f32_32x32x16_bf16(al.v, b0h.v, acc0, 0, 0, 0);
        acc1 = __builtin_amdgcn_mfma_f32_32x32x16_bf16(al.v, b1h.v, acc1, 0, 0, 0);
    }

    // Epilogue. C layout (verified m74/m101 + rounds 3-4):
    // col = lane&31, row = (reg&3) + 8*(reg>>2) + 4*lh.
    const float bb0 = bvec[e0], bb1 = bvec[e0 + 32];
    #pragma unroll
    for (int q = 0; q < 4; q++) {
        #pragma unroll
        for (int j = 0; j < 4; j++) {
            const int reg = q * 4 + j;
            const int r = rowBase + j + 8 * q + 4 * lh;
            const float n0 = noise[(size_t)r * NEXP + e0];
            const float n1 = noise[(size_t)r * NEXP + e0 + 32];
            const float v0 = (acc0[reg] + bb0) + n0;   // ref order: (dot + b) + noise
            const float v1 = (acc1[reg] + bb1) + n1;

            float v1m, v2m, v3m = -1e30f; int e1m, e2m;
            if (beats(v0, e0, v1, e0 + 32)) { v1m = v0; e1m = e0;      v2m = v1; e2m = e0 + 32; }
            else                            { v1m = v1; e1m = e0 + 32; v2m = v0; e2m = e0;      }
            #pragma unroll
            for (int d = 1; d < 32; d <<= 1) {         // butterfly within 32-lane half
                float ov1 = __shfl_xor(v1m, d); int oe1 = __shfl_xor(e1m, d);
                float ov2 = __shfl_xor(v2m, d); int oe2 = __shfl_xor(e2m, d);
                float ov3 = __shfl_xor(v3m, d);
                bool  aw  = beats(v1m, e1m, ov1, oe1);
                float a1v = aw ? v1m : ov1; int a1e = aw ? e1m : oe1;
                float b1v = aw ? ov1 : v1m; int b1e = aw ? oe1 : e1m;
                float a2v = aw ? v2m : ov2; int a2e = aw ? e2m : oe2;
                float b2v = aw ? ov2 : v2m;
                float a3v = aw ? v3m : ov3;
                bool  s2  = beats(a2v, a2e, b1v, b1e);
                v1m = a1v; e1m = a1e;
                v2m = s2 ? a2v : b1v; e2m = s2 ? a2e : b1e;
                v3m = s2 ? fmaxf(a3v, b1v) : fmaxf(a2v, b2v);
            }
            const float t   = __expf(v2m - v1m);
            const float inv = 1.0f / (1.0f + t);
            const float w1  = inv, w2 = t * inv;

            if (e0 == 0 && (v2m - v3m) < TAU) {
                unsigned int idx = atomicAdd(flags, 1u);
                if (idx < CAP) flags[1 + idx] = (unsigned int)r;
            }
            const int c0 = 2 * e0, c1 = c0 + 1;
            const float o0 = (c0 == e1m) ? w1 : (c0 == e2m) ? w2 : 0.0f;
            const float o1 = (c1 == e1m) ? w1 : (c1 == e2m) ? w2 : 0.0f;
            *(float2*)(out + (size_t)r * NEXP + c0) = make_float2(o0, o1);
        }
    }
}

// fp64 re-solve of flagged rows: one 64-lane block per row, lane = expert.
__global__ void gate_repair(const float* __restrict__ x, const float* __restrict__ W,
                            const float* __restrict__ b, const float* __restrict__ noise,
                            float* __restrict__ out, const unsigned int* __restrict__ flags,
                            int D) {
    unsigned int cnt = flags[0];
    if (cnt > CAP) cnt = CAP;
    if (blockIdx.x >= cnt) return;
    const int r = (int)flags[1 + blockIdx.x];
    const int e = threadIdx.x;  // 0..63

    const float* xr = x + (size_t)r * D;
    const float* wr = W + (size_t)e * D;
    double s = 0.0;
    for (int d0 = 0; d0 < D; d0 += 4) {
        float4 xv = *(const float4*)(xr + d0);
        float4 wv = *(const float4*)(wr + d0);
        s += (double)xv.x * (double)wv.x;
        s += (double)xv.y * (double)wv.y;
        s += (double)xv.z * (double)wv.z;
        s += (double)xv.w * (double)wv.w;
    }
    const float clean = (float)s + b[e];
    const float v     = clean + noise[(size_t)r * NEXP + e];

    float v1 = v, v2 = -1e30f; int e1 = e, e2 = 99;
    for (int d = 1; d < 64; d <<= 1) {
        float ov1 = __shfl_xor(v1, d); int oe1 = __shfl_xor(e1, d);
        float ov2 = __shfl_xor(v2, d); int oe2 = __shfl_xor(e2, d);
        bool  aw  = beats(v1, e1, ov1, oe1);
        float a1v = aw ? v1 : ov1; int a1e = aw ? e1 : oe1;
        float b1v = aw ? ov1 : v1; int b1e = aw ? oe1 : e1;
        float a2v = aw ? v2 : ov2; int a2e = aw ? e2 : oe2;
        bool  s2  = beats(a2v, a2e, b1v, b1e);
        v1 = a1v; e1 = a1e;
        v2 = s2 ? a2v : b1v; e2 = s2 ? a2e : b1e;
    }
    const float t   = __expf(v2 - v1);
    const float inv = 1.0f / (1.0f + t);
    out[(size_t)r * NEXP + e] = (e == e1) ? inv : (e == e2) ? t * inv : 0.0f;
}

extern "C" void kernel_launch(void* const* d_in, const int* in_sizes, int n_in,
                              void* d_out, int out_size, void* d_ws, size_t ws_size,
                              hipStream_t stream) {
    const float* x     = (const float*)d_in[0];
    const float* W     = (const float*)d_in[1];
    const float* b     = (const float*)d_in[2];
    const float* noise = (const float*)d_in[3];
    float* out = (float*)d_out;

    const int E = in_sizes[2];       // 64
    const int D = in_sizes[1] / E;   // 1024
    const int N = in_sizes[0] / D;   // 131072

    unsigned int* flags = (unsigned int*)d_ws;
    char* wsW = (char*)d_ws + WS_W_OFF;

    convW_kernel<<<dim3(E), dim3(128), 0, stream>>>(W, wsW);
    hipMemsetAsync(d_ws, 0, sizeof(unsigned int), stream);
    gate_mfma<<<dim3(N / TILE_M), dim3(BLOCK), 0, stream>>>(x, b, noise, wsW, out, flags);
    gate_repair<<<dim3(CAP), dim3(64), 0, stream>>>(x, W, b, noise, out, flags, D);
}

// Round 6
// 238.596 us; speedup vs baseline: 1.1488x; 1.1488x over previous
//
#include <hip/hip_runtime.h>
#include <math.h>

// NoisyTopKGating: out[N,64] = scatter(softmax(top2(x@W^T + b + noise)))
// N=131072, D=1024, E=64, K=2, NOISE_STD=1.0
//
// Round 6: deep async pipeline. Rounds 4/5 were latency-bound (~2.4 TB/s) on
// x-load depth (VGPR-bound prefetch + vmcnt(0) drains / in-order vmcnt mixing).
// Now BOTH x and W stream via global_load_lds (no VGPR cost -> deep vmcnt
// queue), NBUF=3 circular LDS buffers, stage chunk c+1 during compute of c,
// counted s_waitcnt vmcnt(6) + raw s_barrier per chunk (NEVER vmcnt(0) in the
// main loop). x globally pre-swizzled (seg ^= row&7) into linear LDS dest so
// ds_read_b128 fragment reads are bank-uniform (rule #21). logits = xh*wh +
// xh*wl + xl*wh via mfma_f32_32x32x16_bf16 (err ~4e-6 << TAU). fp64 repair
// pass for rows with gap(#2,#3) < TAU (proven rounds 3-5).

#define NEXP   64
#define BLOCK  256
#define TILE_M 128
#define DFIX   1024
#define KCF    32        // K floats per chunk
#define NCH    32        // DFIX / KCF
#define NBUF   3
#define XCHB   16384     // x chunk: 128 rows x 128 B
#define WCHB   8192      // W chunk: 8 frags x 1 KB
#define TAU    1e-3f
#define CAP    4096
#define WS_W_OFF 32768   // frag-major W image at d_ws + 32 KB

typedef __attribute__((ext_vector_type(8)))  short bf16x8;
typedef __attribute__((ext_vector_type(16))) float f32x16;

__device__ __forceinline__ bool beats(float v, int e, float vo, int eo) {
    // jax.lax.top_k ordering: higher value wins, lower index on tie
    return (v > vo) || (v == vo && e < eo);
}

// Split two fp32 into packed bf16-hi pair and bf16-lo (residual) pair, by truncation.
__device__ __forceinline__ void split2(float f0, float f1, unsigned int& hi, unsigned int& lo) {
    unsigned int u0 = __float_as_uint(f0), u1 = __float_as_uint(f1);
    unsigned int h0 = u0 & 0xFFFF0000u,  h1 = u1 & 0xFFFF0000u;
    float l0 = f0 - __uint_as_float(h0);
    float l1 = f1 - __uint_as_float(h1);
    hi = (u0 >> 16) | h1;
    lo = (__float_as_uint(l0) >> 16) | (__float_as_uint(l1) & 0xFFFF0000u);
}

__device__ __forceinline__ void gl_lds16(const void* g, void* l) {
    __builtin_amdgcn_global_load_lds((const __attribute__((address_space(1))) void*)g,
                                     (__attribute__((address_space(3))) void*)l,
                                     16, 0, 0);
}

// W (64x1024 fp32) -> frag-major bf16 hi/lo image (256 KB):
// frag f = kk*4 + g*2 + h (kk = k-step 0..63, g = expert-half, h: 0=hi 1=lo),
// lane l of frag f holds W[e = g*32 + (l&31)][k = kk*16 + (l>>5)*8 .. +8] (16B).
__global__ void convW_kernel(const float* __restrict__ W, char* __restrict__ wsW) {
    const int e = blockIdx.x;        // 0..63
    const int t = threadIdx.x;       // 0..127 = global k-octet
    const float* wp = W + e * DFIX + t * 8;
    float4 a  = *(const float4*)wp;
    float4 bq = *(const float4*)(wp + 4);
    unsigned int h[4], l[4];
    split2(a.x,  a.y,  h[0], l[0]);
    split2(a.z,  a.w,  h[1], l[1]);
    split2(bq.x, bq.y, h[2], l[2]);
    split2(bq.z, bq.w, h[3], l[3]);
    const int kk   = t >> 1;         // k-step 0..63
    const int lh   = t & 1;          // k-octet within k-step
    const int lane = lh * 32 + (e & 31);
    const int g    = e >> 5;
    char* base = wsW + (size_t)(kk * 4 + g * 2) * 1024 + lane * 16;
    *(uint4*)(base)        = make_uint4(h[0], h[1], h[2], h[3]);  // h=0 (hi)
    *(uint4*)(base + 1024) = make_uint4(l[0], l[1], l[2], l[3]);  // h=1 (lo)
}

__global__ __launch_bounds__(BLOCK, 2)
void gate_mfma(const float* __restrict__ x, const float* __restrict__ bvec,
               const float* __restrict__ noise, const char* __restrict__ wsW,
               float* __restrict__ out, unsigned int* __restrict__ flags) {
    __shared__ __align__(16) char lds[NBUF * (XCHB + WCHB)];   // 72 KB -> 2 blocks/CU
    char* xls = lds;                    // 3 x 16 KB
    char* wls = lds + NBUF * XCHB;      // 3 x 8 KB

    const int tid  = threadIdx.x;
    const int wv   = tid >> 6;       // wave 0..3 -> rows [32wv, 32wv+32)
    const int lane = tid & 63;
    const int e0   = lane & 31;      // expert col within half / A-row within wave
    const int lh   = lane >> 5;      // k-octet half selector
    const int blkRow0 = blockIdx.x * TILE_M;
    const int rowBase = blkRow0 + wv * 32;
    const int lr      = wv * 32 + e0;    // this lane's local x row (0..127)

    f32x16 acc0 = (f32x16)0.0f;      // experts 0..31
    f32x16 acc1 = (f32x16)0.0f;      // experts 32..63

    // Stage chunk gc into slot sl: 6 global_load_lds per wave (4 x, 2 W).
    // x LDS slot s holds global seg (s&7)^(row&7) of row s>>3 (pre-swizzled
    // source, linear dest). W frags are already frag-major: identity copy.
    auto STAGE = [&](int gc, int sl) {
        char* xb = xls + sl * XCHB;
        char* wb = wls + sl * WCHB;
        const size_t kbyte = (size_t)gc * (KCF * 4);        // 128 B into each row
        #pragma unroll
        for (int j = 0; j < 4; j++) {
            const int s   = wv * 256 + j * 64 + lane;       // LDS 16B-slot id
            const int row = s >> 3;
            const int sp  = s & 7;
            const int seg = sp ^ (row & 7);
            const char* gp = (const char*)(x + (size_t)(blkRow0 + row) * DFIX)
                             + kbyte + seg * 16;
            gl_lds16(gp, xb + (size_t)(wv * 256 + j * 64) * 16);  // + lane*16 by HW
        }
        #pragma unroll
        for (int i = 0; i < 2; i++) {
            const int fl = wv * 2 + i;
            const char* gp = wsW + (size_t)gc * WCHB + fl * 1024 + lane * 16;
            gl_lds16(gp, wb + fl * 1024);                         // + lane*16 by HW
        }
    };

    auto COMPUTE = [&](int sl) {
        const char* xb = xls + sl * XCHB;
        const char* wb = wls + sl * WCHB;
        #pragma unroll
        for (int ks = 0; ks < 2; ks++) {
            const int t0 = ks * 4 + lh * 2;                 // global seg wanted
            const int4 xq0 = *(const int4*)(xb + lr * 128 + ((t0    ) ^ (lr & 7)) * 16);
            const int4 xq1 = *(const int4*)(xb + lr * 128 + ((t0 + 1) ^ (lr & 7)) * 16);
            const float4 xa = *(const float4*)&xq0;
            const float4 xc = *(const float4*)&xq1;
            union { bf16x8 v; unsigned int u[4]; } ah, al;
            split2(xa.x, xa.y, ah.u[0], al.u[0]);
            split2(xa.z, xa.w, ah.u[1], al.u[1]);
            split2(xc.x, xc.y, ah.u[2], al.u[2]);
            split2(xc.z, xc.w, ah.u[3], al.u[3]);
            union { bf16x8 v; int4 q; } b0h, b0l, b1h, b1l;
            b0h.q = *(const int4*)(wb + (ks * 4 + 0) * 1024 + lane * 16);
            b0l.q = *(const int4*)(wb + (ks * 4 + 1) * 1024 + lane * 16);
            b1h.q = *(const int4*)(wb + (ks * 4 + 2) * 1024 + lane * 16);
            b1l.q = *(const int4*)(wb + (ks * 4 + 3) * 1024 + lane * 16);
            acc0 = __builtin_amdgcn_mfma_f32_32x32x16_bf16(ah.v, b0h.v, acc0, 0, 0, 0);
            acc1 = __builtin_amdgcn_mfma_f32_32x32x16_bf16(ah.v, b1h.v, acc1, 0, 0, 0);
            acc0 = __builtin_amdgcn_mfma_f32_32x32x16_bf16(ah.v, b0l.v, acc0, 0, 0, 0);
            acc1 = __builtin_amdgcn_mfma_f32_32x32x16_bf16(ah.v, b1l.v, acc1, 0, 0, 0);
            acc0 = __builtin_amdgcn_mfma_f32_32x32x16_bf16(al.v, b0h.v, acc0, 0, 0, 0);
            acc1 = __builtin_amdgcn_mfma_f32_32x32x16_bf16(al.v, b1h.v, acc1, 0, 0, 0);
        }
    };

    // Pipeline: stage(c+1) in flight while computing c; vmcnt(6) ensures
    // stage(c) landed (only stage(c+1)'s 6 loads still outstanding).
    STAGE(0, 0);
    int slc = 0;
    #pragma unroll 1
    for (int c = 0; c < NCH - 1; c++) {
        const int sln = (slc + 1 == NBUF) ? 0 : slc + 1;
        STAGE(c + 1, sln);
        asm volatile("s_waitcnt vmcnt(6)" ::: "memory");
        __builtin_amdgcn_s_barrier();
        __builtin_amdgcn_sched_barrier(0);
        COMPUTE(slc);
        slc = sln;
    }
    asm volatile("s_waitcnt vmcnt(0)" ::: "memory");
    __builtin_amdgcn_s_barrier();
    __builtin_amdgcn_sched_barrier(0);
    COMPUTE(slc);

    // Epilogue. C layout (verified m74/m101 + rounds 3-5):
    // col = lane&31, row = (reg&3) + 8*(reg>>2) + 4*lh.
    const float bb0 = bvec[e0], bb1 = bvec[e0 + 32];
    #pragma unroll
    for (int q = 0; q < 4; q++) {
        #pragma unroll
        for (int j = 0; j < 4; j++) {
            const int reg = q * 4 + j;
            const int r = rowBase + j + 8 * q + 4 * lh;
            const float n0 = noise[(size_t)r * NEXP + e0];
            const float n1 = noise[(size_t)r * NEXP + e0 + 32];
            const float v0 = (acc0[reg] + bb0) + n0;   // ref order: (dot + b) + noise
            const float v1 = (acc1[reg] + bb1) + n1;

            float v1m, v2m, v3m = -1e30f; int e1m, e2m;
            if (beats(v0, e0, v1, e0 + 32)) { v1m = v0; e1m = e0;      v2m = v1; e2m = e0 + 32; }
            else                            { v1m = v1; e1m = e0 + 32; v2m = v0; e2m = e0;      }
            #pragma unroll
            for (int d = 1; d < 32; d <<= 1) {         // butterfly within 32-lane half
                float ov1 = __shfl_xor(v1m, d); int oe1 = __shfl_xor(e1m, d);
                float ov2 = __shfl_xor(v2m, d); int oe2 = __shfl_xor(e2m, d);
                float ov3 = __shfl_xor(v3m, d);
                bool  aw  = beats(v1m, e1m, ov1, oe1);
                float a1v = aw ? v1m : ov1; int a1e = aw ? e1m : oe1;
                float b1v = aw ? ov1 : v1m; int b1e = aw ? oe1 : e1m;
                float a2v = aw ? v2m : ov2; int a2e = aw ? e2m : oe2;
                float b2v = aw ? ov2 : v2m;
                float a3v = aw ? v3m : ov3;
                bool  s2  = beats(a2v, a2e, b1v, b1e);
                v1m = a1v; e1m = a1e;
                v2m = s2 ? a2v : b1v; e2m = s2 ? a2e : b1e;
                v3m = s2 ? fmaxf(a3v, b1v) : fmaxf(a2v, b2v);
            }
            const float t   = __expf(v2m - v1m);
            const float inv = 1.0f / (1.0f + t);
            const float w1  = inv, w2 = t * inv;

            if (e0 == 0 && (v2m - v3m) < TAU) {
                unsigned int idx = atomicAdd(flags, 1u);
                if (idx < CAP) flags[1 + idx] = (unsigned int)r;
            }
            const int c0 = 2 * e0, c1 = c0 + 1;
            const float o0 = (c0 == e1m) ? w1 : (c0 == e2m) ? w2 : 0.0f;
            const float o1 = (c1 == e1m) ? w1 : (c1 == e2m) ? w2 : 0.0f;
            *(float2*)(out + (size_t)r * NEXP + c0) = make_float2(o0, o1);
        }
    }
}

// fp64 re-solve of flagged rows: one 64-lane block per row, lane = expert.
__global__ void gate_repair(const float* __restrict__ x, const float* __restrict__ W,
                            const float* __restrict__ b, const float* __restrict__ noise,
                            float* __restrict__ out, const unsigned int* __restrict__ flags,
                            int D) {
    unsigned int cnt = flags[0];
    if (cnt > CAP) cnt = CAP;
    if (blockIdx.x >= cnt) return;
    const int r = (int)flags[1 + blockIdx.x];
    const int e = threadIdx.x;  // 0..63

    const float* xr = x + (size_t)r * D;
    const float* wr = W + (size_t)e * D;
    double s = 0.0;
    for (int d0 = 0; d0 < D; d0 += 4) {
        float4 xv = *(const float4*)(xr + d0);
        float4 wv = *(const float4*)(wr + d0);
        s += (double)xv.x * (double)wv.x;
        s += (double)xv.y * (double)wv.y;
        s += (double)xv.z * (double)wv.z;
        s += (double)xv.w * (double)wv.w;
    }
    const float clean = (float)s + b[e];
    const float v     = clean + noise[(size_t)r * NEXP + e];

    float v1 = v, v2 = -1e30f; int e1 = e, e2 = 99;
    for (int d = 1; d < 64; d <<= 1) {
        float ov1 = __shfl_xor(v1, d); int oe1 = __shfl_xor(e1, d);
        float ov2 = __shfl_xor(v2, d); int oe2 = __shfl_xor(e2, d);
        bool  aw  = beats(v1, e1, ov1, oe1);
        float a1v = aw ? v1 : ov1; int a1e = aw ? e1 : oe1;
        float b1v = aw ? ov1 : v1; int b1e = aw ? oe1 : e1;
        float a2v = aw ? v2 : ov2; int a2e = aw ? e2 : oe2;
        bool  s2  = beats(a2v, a2e, b1v, b1e);
        v1 = a1v; e1 = a1e;
        v2 = s2 ? a2v : b1v; e2 = s2 ? a2e : b1e;
    }
    const float t   = __expf(v2 - v1);
    const float inv = 1.0f / (1.0f + t);
    out[(size_t)r * NEXP + e] = (e == e1) ? inv : (e == e2) ? t * inv : 0.0f;
}

extern "C" void kernel_launch(void* const* d_in, const int* in_sizes, int n_in,
                              void* d_out, int out_size, void* d_ws, size_t ws_size,
                              hipStream_t stream) {
    const float* x     = (const float*)d_in[0];
    const float* W     = (const float*)d_in[1];
    const float* b     = (const float*)d_in[2];
    const float* noise = (const float*)d_in[3];
    float* out = (float*)d_out;

    const int E = in_sizes[2];       // 64
    const int D = in_sizes[1] / E;   // 1024
    const int N = in_sizes[0] / D;   // 131072

    unsigned int* flags = (unsigned int*)d_ws;
    char* wsW = (char*)d_ws + WS_W_OFF;

    convW_kernel<<<dim3(E), dim3(128), 0, stream>>>(W, wsW);
    hipMemsetAsync(d_ws, 0, sizeof(unsigned int), stream);
    gate_mfma<<<dim3(N / TILE_M), dim3(BLOCK), 0, stream>>>(x, b, noise, wsW, out, flags);
    gate_repair<<<dim3(CAP), dim3(64), 0, stream>>>(x, W, b, noise, out, flags, D);
}

// Round 7
// 218.229 us; speedup vs baseline: 1.2561x; 1.0933x over previous
//
#include <hip/hip_runtime.h>
#include <math.h>

// NoisyTopKGating: out[N,64] = scatter(softmax(top2(x@W^T + b + noise)))
// N=131072, D=1024, E=64, K=2, NOISE_STD=1.0
//
// Round 7: R6 + per-block k-phase rotation. R4/R5/R6 all plateau at ~2.4-2.7
// TB/s regardless of sync structure -> bottleneck is the temporally-correlated
// column access: at chunk c every block reads the SAME 128B offset within its
// 4KB rows (power-of-2 stride) -> same HBM pseudo-channel subset chip-wide.
// Fix: block b walks chunks in order (c + b) & 31, spreading concurrent reads
// across all 32 column positions -> all channels. Accumulation-order change is
// ~1e-5 (<< TAU); fp64 repair pass covers ranking (proven rounds 3-6).

#define NEXP   64
#define BLOCK  256
#define TILE_M 128
#define DFIX   1024
#define KCF    32        // K floats per chunk
#define NCH    32        // DFIX / KCF
#define NBUF   3
#define XCHB   16384     // x chunk: 128 rows x 128 B
#define WCHB   8192      // W chunk: 8 frags x 1 KB
#define TAU    1e-3f
#define CAP    4096
#define WS_W_OFF 32768   // frag-major W image at d_ws + 32 KB

typedef __attribute__((ext_vector_type(8)))  short bf16x8;
typedef __attribute__((ext_vector_type(16))) float f32x16;

__device__ __forceinline__ bool beats(float v, int e, float vo, int eo) {
    // jax.lax.top_k ordering: higher value wins, lower index on tie
    return (v > vo) || (v == vo && e < eo);
}

// Split two fp32 into packed bf16-hi pair and bf16-lo (residual) pair, by truncation.
__device__ __forceinline__ void split2(float f0, float f1, unsigned int& hi, unsigned int& lo) {
    unsigned int u0 = __float_as_uint(f0), u1 = __float_as_uint(f1);
    unsigned int h0 = u0 & 0xFFFF0000u,  h1 = u1 & 0xFFFF0000u;
    float l0 = f0 - __uint_as_float(h0);
    float l1 = f1 - __uint_as_float(h1);
    hi = (u0 >> 16) | h1;
    lo = (__float_as_uint(l0) >> 16) | (__float_as_uint(l1) & 0xFFFF0000u);
}

__device__ __forceinline__ void gl_lds16(const void* g, void* l) {
    __builtin_amdgcn_global_load_lds((const __attribute__((address_space(1))) void*)g,
                                     (__attribute__((address_space(3))) void*)l,
                                     16, 0, 0);
}

// W (64x1024 fp32) -> frag-major bf16 hi/lo image (256 KB):
// frag f = kk*4 + g*2 + h (kk = k-step 0..63, g = expert-half, h: 0=hi 1=lo),
// lane l of frag f holds W[e = g*32 + (l&31)][k = kk*16 + (l>>5)*8 .. +8] (16B).
__global__ void convW_kernel(const float* __restrict__ W, char* __restrict__ wsW) {
    const int e = blockIdx.x;        // 0..63
    const int t = threadIdx.x;       // 0..127 = global k-octet
    const float* wp = W + e * DFIX + t * 8;
    float4 a  = *(const float4*)wp;
    float4 bq = *(const float4*)(wp + 4);
    unsigned int h[4], l[4];
    split2(a.x,  a.y,  h[0], l[0]);
    split2(a.z,  a.w,  h[1], l[1]);
    split2(bq.x, bq.y, h[2], l[2]);
    split2(bq.z, bq.w, h[3], l[3]);
    const int kk   = t >> 1;         // k-step 0..63
    const int lh   = t & 1;          // k-octet within k-step
    const int lane = lh * 32 + (e & 31);
    const int g    = e >> 5;
    char* base = wsW + (size_t)(kk * 4 + g * 2) * 1024 + lane * 16;
    *(uint4*)(base)        = make_uint4(h[0], h[1], h[2], h[3]);  // h=0 (hi)
    *(uint4*)(base + 1024) = make_uint4(l[0], l[1], l[2], l[3]);  // h=1 (lo)
}

__global__ __launch_bounds__(BLOCK, 2)
void gate_mfma(const float* __restrict__ x, const float* __restrict__ bvec,
               const float* __restrict__ noise, const char* __restrict__ wsW,
               float* __restrict__ out, unsigned int* __restrict__ flags) {
    __shared__ __align__(16) char lds[NBUF * (XCHB + WCHB)];   // 72 KB -> 2 blocks/CU
    char* xls = lds;                    // 3 x 16 KB
    char* wls = lds + NBUF * XCHB;      // 3 x 8 KB

    const int tid  = threadIdx.x;
    const int wv   = tid >> 6;       // wave 0..3 -> rows [32wv, 32wv+32)
    const int lane = tid & 63;
    const int e0   = lane & 31;      // expert col within half / A-row within wave
    const int lh   = lane >> 5;      // k-octet half selector
    const int blkRow0 = blockIdx.x * TILE_M;
    const int rowBase = blkRow0 + wv * 32;
    const int lr      = wv * 32 + e0;    // this lane's local x row (0..127)
    const int phase   = blockIdx.x & 31; // k-phase rotation (channel decorrelation)

    f32x16 acc0 = (f32x16)0.0f;      // experts 0..31
    f32x16 acc1 = (f32x16)0.0f;      // experts 32..63

    // Stage GLOBAL chunk gc into slot sl: 6 global_load_lds per wave (4 x, 2 W).
    // x LDS slot s holds global seg (s&7)^(row&7) of row s>>3 (pre-swizzled
    // source, linear dest). W frags are already frag-major: identity copy.
    auto STAGE = [&](int gc, int sl) {
        char* xb = xls + sl * XCHB;
        char* wb = wls + sl * WCHB;
        const size_t kbyte = (size_t)gc * (KCF * 4);        // 128 B into each row
        #pragma unroll
        for (int j = 0; j < 4; j++) {
            const int s   = wv * 256 + j * 64 + lane;       // LDS 16B-slot id
            const int row = s >> 3;
            const int sp  = s & 7;
            const int seg = sp ^ (row & 7);
            const char* gp = (const char*)(x + (size_t)(blkRow0 + row) * DFIX)
                             + kbyte + seg * 16;
            gl_lds16(gp, xb + (size_t)(wv * 256 + j * 64) * 16);  // + lane*16 by HW
        }
        #pragma unroll
        for (int i = 0; i < 2; i++) {
            const int fl = wv * 2 + i;
            const char* gp = wsW + (size_t)gc * WCHB + fl * 1024 + lane * 16;
            gl_lds16(gp, wb + fl * 1024);                         // + lane*16 by HW
        }
    };

    auto COMPUTE = [&](int sl) {
        const char* xb = xls + sl * XCHB;
        const char* wb = wls + sl * WCHB;
        #pragma unroll
        for (int ks = 0; ks < 2; ks++) {
            const int t0 = ks * 4 + lh * 2;                 // global seg wanted
            const int4 xq0 = *(const int4*)(xb + lr * 128 + ((t0    ) ^ (lr & 7)) * 16);
            const int4 xq1 = *(const int4*)(xb + lr * 128 + ((t0 + 1) ^ (lr & 7)) * 16);
            const float4 xa = *(const float4*)&xq0;
            const float4 xc = *(const float4*)&xq1;
            union { bf16x8 v; unsigned int u[4]; } ah, al;
            split2(xa.x, xa.y, ah.u[0], al.u[0]);
            split2(xa.z, xa.w, ah.u[1], al.u[1]);
            split2(xc.x, xc.y, ah.u[2], al.u[2]);
            split2(xc.z, xc.w, ah.u[3], al.u[3]);
            union { bf16x8 v; int4 q; } b0h, b0l, b1h, b1l;
            b0h.q = *(const int4*)(wb + (ks * 4 + 0) * 1024 + lane * 16);
            b0l.q = *(const int4*)(wb + (ks * 4 + 1) * 1024 + lane * 16);
            b1h.q = *(const int4*)(wb + (ks * 4 + 2) * 1024 + lane * 16);
            b1l.q = *(const int4*)(wb + (ks * 4 + 3) * 1024 + lane * 16);
            acc0 = __builtin_amdgcn_mfma_f32_32x32x16_bf16(ah.v, b0h.v, acc0, 0, 0, 0);
            acc1 = __builtin_amdgcn_mfma_f32_32x32x16_bf16(ah.v, b1h.v, acc1, 0, 0, 0);
            acc0 = __builtin_amdgcn_mfma_f32_32x32x16_bf16(ah.v, b0l.v, acc0, 0, 0, 0);
            acc1 = __builtin_amdgcn_mfma_f32_32x32x16_bf16(ah.v, b1l.v, acc1, 0, 0, 0);
            acc0 = __builtin_amdgcn_mfma_f32_32x32x16_bf16(al.v, b0h.v, acc0, 0, 0, 0);
            acc1 = __builtin_amdgcn_mfma_f32_32x32x16_bf16(al.v, b1h.v, acc1, 0, 0, 0);
        }
    };

    // Pipeline (race-free with NBUF=3, 1-ahead staging; barrier ordering proven
    // in R6 analysis): stage(c+1) in flight while computing c; vmcnt(6) ensures
    // stage(c) landed (only stage(c+1)'s 6 loads still outstanding).
    // Global chunk order rotated per block: gc = (c + phase) & 31.
    STAGE(phase, 0);
    int slc = 0;
    #pragma unroll 1
    for (int c = 0; c < NCH - 1; c++) {
        const int sln = (slc + 1 == NBUF) ? 0 : slc + 1;
        STAGE((c + 1 + phase) & (NCH - 1), sln);
        asm volatile("s_waitcnt vmcnt(6)" ::: "memory");
        __builtin_amdgcn_s_barrier();
        __builtin_amdgcn_sched_barrier(0);
        COMPUTE(slc);
        slc = sln;
    }
    asm volatile("s_waitcnt vmcnt(0)" ::: "memory");
    __builtin_amdgcn_s_barrier();
    __builtin_amdgcn_sched_barrier(0);
    COMPUTE(slc);

    // Epilogue. C layout (verified m74/m101 + rounds 3-6):
    // col = lane&31, row = (reg&3) + 8*(reg>>2) + 4*lh.
    const float bb0 = bvec[e0], bb1 = bvec[e0 + 32];
    #pragma unroll
    for (int q = 0; q < 4; q++) {
        #pragma unroll
        for (int j = 0; j < 4; j++) {
            const int reg = q * 4 + j;
            const int r = rowBase + j + 8 * q + 4 * lh;
            const float n0 = noise[(size_t)r * NEXP + e0];
            const float n1 = noise[(size_t)r * NEXP + e0 + 32];
            const float v0 = (acc0[reg] + bb0) + n0;   // ref order: (dot + b) + noise
            const float v1 = (acc1[reg] + bb1) + n1;

            float v1m, v2m, v3m = -1e30f; int e1m, e2m;
            if (beats(v0, e0, v1, e0 + 32)) { v1m = v0; e1m = e0;      v2m = v1; e2m = e0 + 32; }
            else                            { v1m = v1; e1m = e0 + 32; v2m = v0; e2m = e0;      }
            #pragma unroll
            for (int d = 1; d < 32; d <<= 1) {         // butterfly within 32-lane half
                float ov1 = __shfl_xor(v1m, d); int oe1 = __shfl_xor(e1m, d);
                float ov2 = __shfl_xor(v2m, d); int oe2 = __shfl_xor(e2m, d);
                float ov3 = __shfl_xor(v3m, d);
                bool  aw  = beats(v1m, e1m, ov1, oe1);
                float a1v = aw ? v1m : ov1; int a1e = aw ? e1m : oe1;
                float b1v = aw ? ov1 : v1m; int b1e = aw ? oe1 : e1m;
                float a2v = aw ? v2m : ov2; int a2e = aw ? e2m : oe2;
                float b2v = aw ? ov2 : v2m;
                float a3v = aw ? v3m : ov3;
                bool  s2  = beats(a2v, a2e, b1v, b1e);
                v1m = a1v; e1m = a1e;
                v2m = s2 ? a2v : b1v; e2m = s2 ? a2e : b1e;
                v3m = s2 ? fmaxf(a3v, b1v) : fmaxf(a2v, b2v);
            }
            const float t   = __expf(v2m - v1m);
            const float inv = 1.0f / (1.0f + t);
            const float w1  = inv, w2 = t * inv;

            if (e0 == 0 && (v2m - v3m) < TAU) {
                unsigned int idx = atomicAdd(flags, 1u);
                if (idx < CAP) flags[1 + idx] = (unsigned int)r;
            }
            const int c0 = 2 * e0, c1 = c0 + 1;
            const float o0 = (c0 == e1m) ? w1 : (c0 == e2m) ? w2 : 0.0f;
            const float o1 = (c1 == e1m) ? w1 : (c1 == e2m) ? w2 : 0.0f;
            *(float2*)(out + (size_t)r * NEXP + c0) = make_float2(o0, o1);
        }
    }
}

// fp64 re-solve of flagged rows: one 64-lane block per row, lane = expert.
__global__ void gate_repair(const float* __restrict__ x, const float* __restrict__ W,
                            const float* __restrict__ b, const float* __restrict__ noise,
                            float* __restrict__ out, const unsigned int* __restrict__ flags,
                            int D) {
    unsigned int cnt = flags[0];
    if (cnt > CAP) cnt = CAP;
    if (blockIdx.x >= cnt) return;
    const int r = (int)flags[1 + blockIdx.x];
    const int e = threadIdx.x;  // 0..63

    const float* xr = x + (size_t)r * D;
    const float* wr = W + (size_t)e * D;
    double s = 0.0;
    for (int d0 = 0; d0 < D; d0 += 4) {
        float4 xv = *(const float4*)(xr + d0);
        float4 wv = *(const float4*)(wr + d0);
        s += (double)xv.x * (double)wv.x;
        s += (double)xv.y * (double)wv.y;
        s += (double)xv.z * (double)wv.z;
        s += (double)xv.w * (double)wv.w;
    }
    const float clean = (float)s + b[e];
    const float v     = clean + noise[(size_t)r * NEXP + e];

    float v1 = v, v2 = -1e30f; int e1 = e, e2 = 99;
    for (int d = 1; d < 64; d <<= 1) {
        float ov1 = __shfl_xor(v1, d); int oe1 = __shfl_xor(e1, d);
        float ov2 = __shfl_xor(v2, d); int oe2 = __shfl_xor(e2, d);
        bool  aw  = beats(v1, e1, ov1, oe1);
        float a1v = aw ? v1 : ov1; int a1e = aw ? e1 : oe1;
        float b1v = aw ? ov1 : v1; int b1e = aw ? oe1 : e1;
        float a2v = aw ? v2 : ov2; int a2e = aw ? e2 : oe2;
        bool  s2  = beats(a2v, a2e, b1v, b1e);
        v1 = a1v; e1 = a1e;
        v2 = s2 ? a2v : b1v; e2 = s2 ? a2e : b1e;
    }
    const float t   = __expf(v2 - v1);
    const float inv = 1.0f / (1.0f + t);
    out[(size_t)r * NEXP + e] = (e == e1) ? inv : (e == e2) ? t * inv : 0.0f;
}

extern "C" void kernel_launch(void* const* d_in, const int* in_sizes, int n_in,
                              void* d_out, int out_size, void* d_ws, size_t ws_size,
                              hipStream_t stream) {
    const float* x     = (const float*)d_in[0];
    const float* W     = (const float*)d_in[1];
    const float* b     = (const float*)d_in[2];
    const float* noise = (const float*)d_in[3];
    float* out = (float*)d_out;

    const int E = in_sizes[2];       // 64
    const int D = in_sizes[1] / E;   // 1024
    const int N = in_sizes[0] / D;   // 131072

    unsigned int* flags = (unsigned int*)d_ws;
    char* wsW = (char*)d_ws + WS_W_OFF;

    convW_kernel<<<dim3(E), dim3(128), 0, stream>>>(W, wsW);
    hipMemsetAsync(d_ws, 0, sizeof(unsigned int), stream);
    gate_mfma<<<dim3(N / TILE_M), dim3(BLOCK), 0, stream>>>(x, b, noise, wsW, out, flags);
    gate_repair<<<dim3(CAP), dim3(64), 0, stream>>>(x, W, b, noise, out, flags, D);
}

// Round 9
// 204.780 us; speedup vs baseline: 1.3386x; 1.0657x over previous
//
#include <hip/hip_runtime.h>
#include <math.h>

// NoisyTopKGating: out[N,64] = scatter(softmax(top2(x@W^T + b + noise)))
// N=131072, D=1024, E=64, K=2, NOISE_STD=1.0
//
// Round 9 = Round 8 + epilogue barrier fix. R8's logits exchange used a raw
// s_barrier between ds_writes and cross-wave ds_reads -> no memory fence
// (compiler hoist + no lgkmcnt drain) -> stale LDS read -> absmax 0.797.
// Fixed with __syncthreads(). GEMM structure unchanged (clean granule test):
// 512B per row per visit (KCF=128), TILE_M=64, x-only LDS double buffer,
// W preloaded per-chunk into regs from L2-resident frag-major image, counted
// vmcnt(8) (never 0 in-loop), dual barrier per chunk, per-block k-phase
// rotation. logits = xh*wh + xh*wl + xl*wh (err ~4e-6 << TAU); fp64 repair
// pass for rows with gap(#2,#3) < TAU (proven rounds 3-7).

#define NEXP   64
#define BLOCK  256
#define TILE_M 64
#define DFIX   1024
#define KCF    128       // K floats per chunk -> 512 B per row per visit
#define NCH    8         // DFIX / KCF
#define XCHB   32768     // x chunk: 64 rows x 512 B
#define TAU    1e-3f
#define CAP    4096
#define WS_W_OFF 32768   // frag-major W image at d_ws + 32 KB

typedef __attribute__((ext_vector_type(8)))  short bf16x8;
typedef __attribute__((ext_vector_type(16))) float f32x16;

__device__ __forceinline__ bool beats(float v, int e, float vo, int eo) {
    // jax.lax.top_k ordering: higher value wins, lower index on tie
    return (v > vo) || (v == vo && e < eo);
}

// Split two fp32 into packed bf16-hi pair and bf16-lo (residual) pair, by truncation.
__device__ __forceinline__ void split2(float f0, float f1, unsigned int& hi, unsigned int& lo) {
    unsigned int u0 = __float_as_uint(f0), u1 = __float_as_uint(f1);
    unsigned int h0 = u0 & 0xFFFF0000u,  h1 = u1 & 0xFFFF0000u;
    float l0 = f0 - __uint_as_float(h0);
    float l1 = f1 - __uint_as_float(h1);
    hi = (u0 >> 16) | h1;
    lo = (__float_as_uint(l0) >> 16) | (__float_as_uint(l1) & 0xFFFF0000u);
}

__device__ __forceinline__ void gl_lds16(const void* g, void* l) {
    __builtin_amdgcn_global_load_lds((const __attribute__((address_space(1))) void*)g,
                                     (__attribute__((address_space(3))) void*)l,
                                     16, 0, 0);
}

// W (64x1024 fp32) -> frag-major bf16 hi/lo image (256 KB):
// frag f = kk*4 + g*2 + h (kk = k-step 0..63, g = expert-half, h: 0=hi 1=lo),
// lane l of frag f holds W[e = g*32 + (l&31)][k = kk*16 + (l>>5)*8 .. +8] (16B).
__global__ void convW_kernel(const float* __restrict__ W, char* __restrict__ wsW) {
    const int e = blockIdx.x;        // 0..63
    const int t = threadIdx.x;       // 0..127 = global k-octet
    const float* wp = W + e * DFIX + t * 8;
    float4 a  = *(const float4*)wp;
    float4 bq = *(const float4*)(wp + 4);
    unsigned int h[4], l[4];
    split2(a.x,  a.y,  h[0], l[0]);
    split2(a.z,  a.w,  h[1], l[1]);
    split2(bq.x, bq.y, h[2], l[2]);
    split2(bq.z, bq.w, h[3], l[3]);
    const int kk   = t >> 1;         // k-step 0..63
    const int lh   = t & 1;          // k-octet within k-step
    const int lane = lh * 32 + (e & 31);
    const int g    = e >> 5;
    char* base = wsW + (size_t)(kk * 4 + g * 2) * 1024 + lane * 16;
    *(uint4*)(base)        = make_uint4(h[0], h[1], h[2], h[3]);  // h=0 (hi)
    *(uint4*)(base + 1024) = make_uint4(l[0], l[1], l[2], l[3]);  // h=1 (lo)
}

__global__ __launch_bounds__(BLOCK, 2)
void gate_mfma(const float* __restrict__ x, const float* __restrict__ bvec,
               const float* __restrict__ noise, const char* __restrict__ wsW,
               float* __restrict__ out, unsigned int* __restrict__ flags) {
    __shared__ __align__(16) char lds[2 * XCHB];   // 64 KB -> 2 blocks/CU

    const int tid  = threadIdx.x;
    const int wv   = tid >> 6;       // wave 0..3
    const int lane = tid & 63;
    const int e0   = lane & 31;
    const int lh   = lane >> 5;      // k-octet half selector
    const int rg   = wv & 1;         // row group: rows rg*32..+32
    const int cg   = wv >> 1;        // col group: experts cg*32..+32
    const int blkRow0 = blockIdx.x * TILE_M;
    const int rowL  = rg * 32 + e0;  // this lane's A row within tile (0..63)
    const int phase = blockIdx.x & (NCH - 1);   // k-phase rotation (R7)

    f32x16 acc = (f32x16)0.0f;       // 32 rows x 32 experts per wave

    // Stage GLOBAL chunk gc (512B per row) into buffer buf: 8 gl_lds16/wave.
    // LDS slot (row, seg) holds global seg (seg ^ (row&31)) of that row
    // (inverse-swizzled source, linear dest; XOR is the involution).
    auto STAGE = [&](int gc, int buf) {
        char* xb = lds + buf * XCHB;
        #pragma unroll
        for (int j = 0; j < 8; j++) {
            const int s   = j * 256 + wv * 64 + lane;   // 16B-slot id 0..2047
            const int row = s >> 5;
            const int seg = (s & 31) ^ (row & 31);
            const char* gp = (const char*)(x + (size_t)(blkRow0 + row) * DFIX)
                             + (size_t)gc * 512 + seg * 16;
            gl_lds16(gp, xb + (size_t)(j * 256 + wv * 64) * 16);  // +lane*16 by HW
        }
    };

    // Per-chunk W fragments (this wave's col group, hi+lo, 8 ksteps) -> regs.
    // Issued BEFORE the next STAGE so in-order vmcnt retirement keeps the
    // hand count exact: vmcnt(8) == stage(c)+W(c) done, stage(c+1) in flight.
    int4 wreg[16];
    auto WPRE = [&](int gc) {
        const char* base = wsW + (size_t)(gc * 32 + cg * 2) * 1024 + lane * 16;
        #pragma unroll
        for (int ks = 0; ks < 8; ks++) {
            wreg[ks * 2 + 0] = *(const int4*)(base + (ks * 4 + 0) * 1024);  // hi
            wreg[ks * 2 + 1] = *(const int4*)(base + (ks * 4 + 1) * 1024);  // lo
        }
    };

    auto COMPUTE = [&](int buf) {
        const char* xb = lds + buf * XCHB;
        #pragma unroll
        for (int ks = 0; ks < 8; ks++) {
            const int g0 = ks * 4 + lh * 2;             // global seg wanted
            const int4 xq0 = *(const int4*)(xb + rowL * 512 + ((g0    ) ^ (rowL & 31)) * 16);
            const int4 xq1 = *(const int4*)(xb + rowL * 512 + ((g0 + 1) ^ (rowL & 31)) * 16);
            const float4 xa = *(const float4*)&xq0;
            const float4 xc = *(const float4*)&xq1;
            union { bf16x8 v; unsigned int u[4]; } ah, al;
            split2(xa.x, xa.y, ah.u[0], al.u[0]);
            split2(xa.z, xa.w, ah.u[1], al.u[1]);
            split2(xc.x, xc.y, ah.u[2], al.u[2]);
            split2(xc.z, xc.w, ah.u[3], al.u[3]);
            union { bf16x8 v; int4 q; } bh, bl;
            bh.q = wreg[ks * 2 + 0];
            bl.q = wreg[ks * 2 + 1];
            acc = __builtin_amdgcn_mfma_f32_32x32x16_bf16(ah.v, bh.v, acc, 0, 0, 0);
            acc = __builtin_amdgcn_mfma_f32_32x32x16_bf16(ah.v, bl.v, acc, 0, 0, 0);
            acc = __builtin_amdgcn_mfma_f32_32x32x16_bf16(al.v, bh.v, acc, 0, 0, 0);
        }
    };

    // Pipeline: NBUF=2, dual barrier per chunk (2nd barrier protects buf reuse).
    STAGE(phase, 0);
    #pragma unroll 1
    for (int c = 0; c < NCH - 1; c++) {
        WPRE((c + phase) & (NCH - 1));
        STAGE((c + 1 + phase) & (NCH - 1), (c + 1) & 1);
        asm volatile("s_waitcnt vmcnt(8)" ::: "memory");
        __builtin_amdgcn_s_barrier();
        __builtin_amdgcn_sched_barrier(0);
        COMPUTE(c & 1);
        __builtin_amdgcn_s_barrier();   // all waves done reading buf (c&1)
    }
    WPRE((NCH - 1 + phase) & (NCH - 1));
    asm volatile("s_waitcnt vmcnt(0)" ::: "memory");
    __builtin_amdgcn_s_barrier();
    __builtin_amdgcn_sched_barrier(0);
    COMPUTE((NCH - 1) & 1);

    // ---- Epilogue: logits -> LDS (swizzled 16B slots), cross-wave top-k ----
    // C layout (verified m74/m101 + rounds 3-7): col = lane&31,
    // row = (reg&3) + 8*(reg>>2) + 4*lh.  Writes go to buf0 region (16 KB),
    // disjoint from buf1 still being read by other waves in final COMPUTE.
    const float bb = bvec[cg * 32 + e0];
    #pragma unroll
    for (int q = 0; q < 4; q++) {
        #pragma unroll
        for (int j = 0; j < 4; j++) {
            const int reg = q * 4 + j;
            const int rl  = rg * 32 + j + 8 * q + 4 * lh;   // row local 0..63
            const int r   = blkRow0 + rl;
            const int col = cg * 32 + e0;
            const float v = (acc[reg] + bb) + noise[(size_t)r * NEXP + col];
            const int slot = (col >> 2) ^ (rl & 15);        // bank-spread swizzle
            *(float*)(lds + rl * 256 + slot * 16 + (col & 3) * 4) = v;
        }
    }
    // R8 BUG WAS HERE: raw s_barrier has no memory-fence semantics (compiler
    // may hoist the reads; HW doesn't drain lgkmcnt) -> stale LDS. Full sync:
    __syncthreads();

    // Thread-quad per row: tid>>2 = row, tid&3 = 16-expert span; local top-3,
    // then 2-step xor-shuffle merge (all 4 threads end with the full top-3).
    {
        const int trow = tid >> 2;
        const int qd   = tid & 3;
        float v1 = -1e30f, v2 = -1e30f, v3 = -1e30f;
        int   e1 = 99, e2 = 99;
        #pragma unroll
        for (int i = 0; i < 4; i++) {
            const int slot = (qd * 4 + i) ^ (trow & 15);
            const float4 f = *(const float4*)(lds + trow * 256 + slot * 16);
            #pragma unroll
            for (int m = 0; m < 4; m++) {
                const float v = (m == 0) ? f.x : (m == 1) ? f.y : (m == 2) ? f.z : f.w;
                const int   e = qd * 16 + i * 4 + m;
                if (beats(v, e, v1, e1))      { v3 = v2; v2 = v1; e2 = e1; v1 = v; e1 = e; }
                else if (beats(v, e, v2, e2)) { v3 = v2; v2 = v;  e2 = e; }
                else                          { v3 = fmaxf(v3, v); }
            }
        }
        #pragma unroll
        for (int d = 1; d < 4; d <<= 1) {
            float ov1 = __shfl_xor(v1, d); int oe1 = __shfl_xor(e1, d);
            float ov2 = __shfl_xor(v2, d); int oe2 = __shfl_xor(e2, d);
            float ov3 = __shfl_xor(v3, d);
            bool  aw  = beats(v1, e1, ov1, oe1);
            float a1v = aw ? v1 : ov1; int a1e = aw ? e1 : oe1;
            float b1v = aw ? ov1 : v1; int b1e = aw ? oe1 : e1;
            float a2v = aw ? v2 : ov2; int a2e = aw ? e2 : oe2;
            float b2v = aw ? ov2 : v2;
            float a3v = aw ? v3 : ov3;
            bool  s2  = beats(a2v, a2e, b1v, b1e);
            v1 = a1v; e1 = a1e;
            v2 = s2 ? a2v : b1v; e2 = s2 ? a2e : b1e;
            v3 = s2 ? fmaxf(a3v, b1v) : fmaxf(a2v, b2v);
        }
        const float t   = __expf(v2 - v1);
        const float inv = 1.0f / (1.0f + t);
        const float w1  = inv, w2 = t * inv;
        const int   r   = blkRow0 + trow;

        if (qd == 0 && (v2 - v3) < TAU) {
            unsigned int idx = atomicAdd(flags, 1u);
            if (idx < CAP) flags[1 + idx] = (unsigned int)r;
        }
        float* op = out + (size_t)r * NEXP + qd * 16;
        #pragma unroll
        for (int i = 0; i < 4; i++) {
            float o[4];
            #pragma unroll
            for (int m = 0; m < 4; m++) {
                const int e = qd * 16 + i * 4 + m;
                o[m] = (e == e1) ? w1 : (e == e2) ? w2 : 0.0f;
            }
            *(float4*)(op + i * 4) = make_float4(o[0], o[1], o[2], o[3]);
        }
    }
}

// fp64 re-solve of flagged rows: one 64-lane block per row, lane = expert.
__global__ void gate_repair(const float* __restrict__ x, const float* __restrict__ W,
                            const float* __restrict__ b, const float* __restrict__ noise,
                            float* __restrict__ out, const unsigned int* __restrict__ flags,
                            int D) {
    unsigned int cnt = flags[0];
    if (cnt > CAP) cnt = CAP;
    if (blockIdx.x >= cnt) return;
    const int r = (int)flags[1 + blockIdx.x];
    const int e = threadIdx.x;  // 0..63

    const float* xr = x + (size_t)r * D;
    const float* wr = W + (size_t)e * D;
    double s = 0.0;
    for (int d0 = 0; d0 < D; d0 += 4) {
        float4 xv = *(const float4*)(xr + d0);
        float4 wv = *(const float4*)(wr + d0);
        s += (double)xv.x * (double)wv.x;
        s += (double)xv.y * (double)wv.y;
        s += (double)xv.z * (double)wv.z;
        s += (double)xv.w * (double)wv.w;
    }
    const float clean = (float)s + b[e];
    const float v     = clean + noise[(size_t)r * NEXP + e];

    float v1 = v, v2 = -1e30f; int e1 = e, e2 = 99;
    for (int d = 1; d < 64; d <<= 1) {
        float ov1 = __shfl_xor(v1, d); int oe1 = __shfl_xor(e1, d);
        float ov2 = __shfl_xor(v2, d); int oe2 = __shfl_xor(e2, d);
        bool  aw  = beats(v1, e1, ov1, oe1);
        float a1v = aw ? v1 : ov1; int a1e = aw ? e1 : oe1;
        float b1v = aw ? ov1 : v1; int b1e = aw ? oe1 : e1;
        float a2v = aw ? v2 : ov2; int a2e = aw ? e2 : oe2;
        bool  s2  = beats(a2v, a2e, b1v, b1e);
        v1 = a1v; e1 = a1e;
        v2 = s2 ? a2v : b1v; e2 = s2 ? a2e : b1e;
    }
    const float t   = __expf(v2 - v1);
    const float inv = 1.0f / (1.0f + t);
    out[(size_t)r * NEXP + e] = (e == e1) ? inv : (e == e2) ? t * inv : 0.0f;
}

extern "C" void kernel_launch(void* const* d_in, const int* in_sizes, int n_in,
                              void* d_out, int out_size, void* d_ws, size_t ws_size,
                              hipStream_t stream) {
    const float* x     = (const float*)d_in[0];
    const float* W     = (const float*)d_in[1];
    const float* b     = (const float*)d_in[2];
    const float* noise = (const float*)d_in[3];
    float* out = (float*)d_out;

    const int E = in_sizes[2];       // 64
    const int D = in_sizes[1] / E;   // 1024
    const int N = in_sizes[0] / D;   // 131072

    unsigned int* flags = (unsigned int*)d_ws;
    char* wsW = (char*)d_ws + WS_W_OFF;

    convW_kernel<<<dim3(E), dim3(128), 0, stream>>>(W, wsW);
    hipMemsetAsync(d_ws, 0, sizeof(unsigned int), stream);
    gate_mfma<<<dim3(N / TILE_M), dim3(BLOCK), 0, stream>>>(x, b, noise, wsW, out, flags);
    gate_repair<<<dim3(CAP), dim3(64), 0, stream>>>(x, W, b, noise, out, flags, D);
}